// Round 3
// baseline (3514.347 us; speedup 1.0000x reference)
//
#include <hip/hip_runtime.h>

#define N_NODES  1000000
#define N_EDGES  32000000
#define N_GRAPHS 1024
#define N_LAYERS 8
#define OUT_COLS (N_LAYERS + 1)

#define BKT_SHIFT 10
#define BKT_SIZE  1024
#define NB        977            // ceil(1e6 / 1024)
#define SCAT_BLOCKS 2048
#define SCAT_CHUNK  (N_EDGES / SCAT_BLOCKS)   // 15625 exactly

// ---------------------------------------------------------------------------
// Wave-segmented accumulation of per-graph sums (graph_ids sorted, so most
// 64-lane waves are gid-uniform -> one atomic per wave).
// ---------------------------------------------------------------------------
__device__ inline void seg_accum(int gid, float val, float* __restrict__ out, int col) {
    int g0 = __shfl(gid, 0);
    if (__all(gid == g0)) {
        #pragma unroll
        for (int off = 32; off > 0; off >>= 1)
            val += __shfl_down(val, off);
        if ((threadIdx.x & 63) == 0)
            atomicAdd(&out[g0 * OUT_COLS + col], val);
    } else {
        atomicAdd(&out[gid * OUT_COLS + col], val);
    }
}

// ------------------------- preprocessing: binning --------------------------

// P1: global bucket histogram (LDS-privatized, int4-vectorized)
__global__ void count_kernel(const int4* __restrict__ dst4, unsigned* __restrict__ g_count) {
    __shared__ unsigned hist[BKT_SIZE];
    for (int j = threadIdx.x; j < BKT_SIZE; j += blockDim.x) hist[j] = 0u;
    __syncthreads();
    int stride = gridDim.x * blockDim.x;
    for (int t = blockIdx.x * blockDim.x + threadIdx.x; t < N_EDGES / 4; t += stride) {
        int4 d = dst4[t];
        atomicAdd(&hist[((unsigned)d.x) >> BKT_SHIFT], 1u);
        atomicAdd(&hist[((unsigned)d.y) >> BKT_SHIFT], 1u);
        atomicAdd(&hist[((unsigned)d.z) >> BKT_SHIFT], 1u);
        atomicAdd(&hist[((unsigned)d.w) >> BKT_SHIFT], 1u);
    }
    __syncthreads();
    for (int j = threadIdx.x; j < BKT_SIZE; j += blockDim.x)
        if (hist[j]) atomicAdd(&g_count[j], hist[j]);
}

// P2: exclusive scan of 1024 bucket counts (single block)
__global__ void scan_kernel(const unsigned* __restrict__ g_count,
                            unsigned* __restrict__ g_base,
                            unsigned* __restrict__ g_cursor) {
    __shared__ unsigned s[BKT_SIZE];
    int t = threadIdx.x;
    unsigned c = g_count[t];
    s[t] = c;
    __syncthreads();
    for (int off = 1; off < BKT_SIZE; off <<= 1) {
        unsigned v = (t >= off) ? s[t - off] : 0u;
        __syncthreads();
        s[t] += v;
        __syncthreads();
    }
    unsigned incl = s[t];
    g_base[t]   = incl - c;
    g_cursor[t] = incl - c;
    if (t == BKT_SIZE - 1) g_base[BKT_SIZE] = incl;
}

// P3: scatter edges into bucket-contiguous u64 records.
// rec = (src | dst_low10 << 20) << 32 | f32bits(weight)
__global__ void scatter_kernel(const int* __restrict__ src,
                               const int* __restrict__ dst,
                               const float* __restrict__ ew,
                               unsigned* __restrict__ g_cursor,
                               unsigned long long* __restrict__ recs) {
    __shared__ unsigned lhist[BKT_SIZE];
    __shared__ unsigned lbase[BKT_SIZE];
    int e0 = blockIdx.x * SCAT_CHUNK;
    int e1 = e0 + SCAT_CHUNK;
    for (int j = threadIdx.x; j < BKT_SIZE; j += blockDim.x) lhist[j] = 0u;
    __syncthreads();
    for (int e = e0 + threadIdx.x; e < e1; e += blockDim.x)
        atomicAdd(&lhist[((unsigned)dst[e]) >> BKT_SHIFT], 1u);
    __syncthreads();
    for (int j = threadIdx.x; j < BKT_SIZE; j += blockDim.x) {
        unsigned c = lhist[j];
        lbase[j] = c ? atomicAdd(&g_cursor[j], c) : 0u;
    }
    __syncthreads();
    for (int j = threadIdx.x; j < BKT_SIZE; j += blockDim.x) lhist[j] = 0u;  // reuse as cursor
    __syncthreads();
    for (int e = e0 + threadIdx.x; e < e1; e += blockDim.x) {
        unsigned d = (unsigned)dst[e];
        unsigned b = d >> BKT_SHIFT;
        unsigned loc = atomicAdd(&lhist[b], 1u);
        unsigned pos = lbase[b] + loc;
        unsigned hi  = ((unsigned)src[e]) | ((d & (BKT_SIZE - 1u)) << 20);
        unsigned long long rec = ((unsigned long long)hi << 32) | (unsigned)__float_as_uint(ew[e]);
        __builtin_nontemporal_store(rec, &recs[pos]);
    }
}

// ------------------------------ forward pass --------------------------------

// h0 = x; out[:,0] += per-graph sum of x
__global__ void init_kernel(const float* __restrict__ x,
                            const int* __restrict__ gids,
                            float* __restrict__ h0,
                            float* __restrict__ out) {
    int i = blockIdx.x * blockDim.x + threadIdx.x;
    if (i >= N_NODES) return;
    float v = x[i];
    h0[i] = v;
    seg_accum(gids[i], v, out, 0);
}

// One block per bucket: LDS-accumulate in-edges, then fused affine+relu,
// h double-buffer write, and per-graph sum for the block's 1024 owned nodes.
__global__ void layer_kernel(const unsigned long long* __restrict__ recs,
                             const unsigned* __restrict__ g_base,
                             const float* __restrict__ h_old,
                             float* __restrict__ h_new,
                             const int* __restrict__ gids,
                             const float* __restrict__ Wn,
                             const float* __restrict__ bn,
                             const float* __restrict__ Ws,
                             float* __restrict__ out,
                             int l) {
    __shared__ float agg[BKT_SIZE];
    int b = blockIdx.x;
    for (int j = threadIdx.x; j < BKT_SIZE; j += blockDim.x) agg[j] = 0.0f;
    __syncthreads();
    int e0 = (int)g_base[b];
    int e1 = (int)g_base[b + 1];
    for (int e = e0 + threadIdx.x; e < e1; e += blockDim.x) {
        unsigned long long rec = __builtin_nontemporal_load(&recs[e]);
        unsigned hi = (unsigned)(rec >> 32);
        float w  = __uint_as_float((unsigned)rec);
        float hv = h_old[hi & 0xFFFFFu];
        atomicAdd(&agg[hi >> 20], hv * w);
    }
    __syncthreads();
    float wn = Wn[l], bb = bn[l], ws = Ws[l];
    int nbase = b << BKT_SHIFT;
    for (int j = threadIdx.x; j < BKT_SIZE; j += blockDim.x) {
        int n = nbase + j;
        if (n < N_NODES) {
            float hn = fmaxf(fmaf(agg[j], wn, fmaf(h_old[n], ws, bb)), 0.0f);
            h_new[n] = hn;
            seg_accum(gids[n], hn, out, l + 1);
        }
    }
}

// ------------------------- fallback (round-1 path) --------------------------

__global__ void fb_init_kernel(const float* __restrict__ x, const int* __restrict__ gids,
                               float* __restrict__ h, float* __restrict__ agg,
                               float* __restrict__ out) {
    int i = blockIdx.x * blockDim.x + threadIdx.x;
    if (i >= N_NODES) return;
    float v = x[i];
    h[i] = v; agg[i] = 0.0f;
    seg_accum(gids[i], v, out, 0);
}
__global__ void fb_edge_kernel(const int4* __restrict__ src4, const int4* __restrict__ dst4,
                               const float4* __restrict__ ew4, const float* __restrict__ h,
                               float* __restrict__ agg) {
    int t = blockIdx.x * blockDim.x + threadIdx.x;
    if (t >= N_EDGES / 4) return;
    int4 s = src4[t]; int4 d = dst4[t]; float4 w = ew4[t];
    atomicAdd(&agg[d.x], h[s.x] * w.x);
    atomicAdd(&agg[d.y], h[s.y] * w.y);
    atomicAdd(&agg[d.z], h[s.z] * w.z);
    atomicAdd(&agg[d.w], h[s.w] * w.w);
}
__global__ void fb_node_kernel(float* __restrict__ h, float* __restrict__ agg,
                               const int* __restrict__ gids, const float* __restrict__ Wn,
                               const float* __restrict__ bn, const float* __restrict__ Ws,
                               float* __restrict__ out, int l) {
    int i = blockIdx.x * blockDim.x + threadIdx.x;
    if (i >= N_NODES) return;
    float a = agg[i]; agg[i] = 0.0f;
    float hv = h[i];
    float hn = fmaxf(fmaf(a, Wn[l], fmaf(hv, Ws[l], bn[l])), 0.0f);
    h[i] = hn;
    seg_accum(gids[i], hn, out, l + 1);
}

// -----------------------------------------------------------------------------

extern "C" void kernel_launch(void* const* d_in, const int* in_sizes, int n_in,
                              void* d_out, int out_size, void* d_ws, size_t ws_size,
                              hipStream_t stream) {
    const float* x   = (const float*)d_in[0];
    const int*   src = (const int*)  d_in[1];
    const int*   dst = (const int*)  d_in[2];
    const float* ew  = (const float*)d_in[3];
    const int*   gid = (const int*)  d_in[4];
    const float* Wn  = (const float*)d_in[5];
    const float* bn  = (const float*)d_in[6];
    const float* Ws  = (const float*)d_in[7];
    float* out = (float*)d_out;

    hipMemsetAsync(d_out, 0, (size_t)out_size * sizeof(float), stream);

    size_t need = (size_t)N_EDGES * 8   // recs
                + (size_t)N_NODES * 4   // h0
                + (size_t)N_NODES * 4   // h1
                + (size_t)(BKT_SIZE * 3 + 16) * 4;

    if (ws_size < need) {
        // fallback: round-1 atomic path (needs 8 MB)
        float* h   = (float*)d_ws;
        float* agg = (float*)d_ws + N_NODES;
        const int BT = 256;
        const int nb = (N_NODES + BT - 1) / BT;
        const int eb = (N_EDGES / 4 + BT - 1) / BT;
        fb_init_kernel<<<nb, BT, 0, stream>>>(x, gid, h, agg, out);
        for (int l = 0; l < N_LAYERS; ++l) {
            fb_edge_kernel<<<eb, BT, 0, stream>>>(
                (const int4*)src, (const int4*)dst, (const float4*)ew, h, agg);
            fb_node_kernel<<<nb, BT, 0, stream>>>(h, agg, gid, Wn, bn, Ws, out, l);
        }
        return;
    }

    char* p = (char*)d_ws;
    unsigned long long* recs = (unsigned long long*)p;  p += (size_t)N_EDGES * 8;
    float*    h0       = (float*)p;                     p += (size_t)N_NODES * 4;
    float*    h1       = (float*)p;                     p += (size_t)N_NODES * 4;
    unsigned* g_count  = (unsigned*)p;                  p += BKT_SIZE * 4;
    unsigned* g_cursor = (unsigned*)p;                  p += BKT_SIZE * 4;
    unsigned* g_base   = (unsigned*)p;                  p += (BKT_SIZE + 1) * 4;

    // zero counters (g_count and g_cursor are adjacent)
    hipMemsetAsync(g_count, 0, BKT_SIZE * 2 * sizeof(unsigned), stream);

    // binning (once per call, amortized over 8 layers)
    count_kernel  <<<2048, 256, 0, stream>>>((const int4*)dst, g_count);
    scan_kernel   <<<1, BKT_SIZE, 0, stream>>>(g_count, g_base, g_cursor);
    scatter_kernel<<<SCAT_BLOCKS, 256, 0, stream>>>(src, dst, ew, g_cursor, recs);

    // forward
    const int BT = 256;
    const int nb = (N_NODES + BT - 1) / BT;
    init_kernel<<<nb, BT, 0, stream>>>(x, gid, h0, out);

    float* ha = h0;
    float* hb = h1;
    for (int l = 0; l < N_LAYERS; ++l) {
        layer_kernel<<<NB, 512, 0, stream>>>(recs, g_base, ha, hb,
                                             gid, Wn, bn, Ws, out, l);
        float* t = ha; ha = hb; hb = t;
    }
}

// Round 4
// 2265.988 us; speedup vs baseline: 1.5509x; 1.5509x over previous
//
#include <hip/hip_runtime.h>

#define N_NODES  1000000
#define N_EDGES  32000000
#define N_GRAPHS 1024
#define N_LAYERS 8
#define OUT_COLS (N_LAYERS + 1)

#define BKT_SHIFT 11
#define BKT_NODES 2048
#define NBKT      489            // ceil(1e6 / 2048); last bucket has 576 nodes
#define NBKT_PAD  512
#define SCAT_BLOCKS 256
#define SCAT_THREADS 1024
#define SCAT_CHUNK  (N_EDGES / SCAT_BLOCKS)   // 125000 exactly

// ---------------------------------------------------------------------------
// Wave-segmented accumulation of per-graph sums (graph_ids sorted, so most
// 64-lane waves are gid-uniform -> one atomic per wave). All call sites
// guarantee waves are fully active or fully inactive (cuts land on 64-lane
// boundaries because N_NODES % 64 == 0 and bucket bases are 2048-aligned).
// ---------------------------------------------------------------------------
__device__ inline void seg_accum(int gid, float val, float* __restrict__ out, int col) {
    int g0 = __shfl(gid, 0);
    if (__all(gid == g0)) {
        #pragma unroll
        for (int off = 32; off > 0; off >>= 1)
            val += __shfl_down(val, off);
        if ((threadIdx.x & 63) == 0)
            atomicAdd(&out[g0 * OUT_COLS + col], val);
    } else {
        atomicAdd(&out[gid * OUT_COLS + col], val);
    }
}

// ------------------------- preprocessing: binning --------------------------

// P1: global bucket histogram (LDS-privatized, int4-vectorized)
__global__ void count_kernel(const int4* __restrict__ dst4, unsigned* __restrict__ g_count) {
    __shared__ unsigned hist[NBKT_PAD];
    for (int j = threadIdx.x; j < NBKT_PAD; j += blockDim.x) hist[j] = 0u;
    __syncthreads();
    int stride = gridDim.x * blockDim.x;
    for (int t = blockIdx.x * blockDim.x + threadIdx.x; t < N_EDGES / 4; t += stride) {
        int4 d = dst4[t];
        atomicAdd(&hist[((unsigned)d.x) >> BKT_SHIFT], 1u);
        atomicAdd(&hist[((unsigned)d.y) >> BKT_SHIFT], 1u);
        atomicAdd(&hist[((unsigned)d.z) >> BKT_SHIFT], 1u);
        atomicAdd(&hist[((unsigned)d.w) >> BKT_SHIFT], 1u);
    }
    __syncthreads();
    for (int j = threadIdx.x; j < NBKT_PAD; j += blockDim.x)
        if (hist[j]) atomicAdd(&g_count[j], hist[j]);
}

// P2: exclusive scan of padded bucket counts (single block of NBKT_PAD threads)
__global__ void scan_kernel(const unsigned* __restrict__ g_count,
                            unsigned* __restrict__ g_base,
                            unsigned* __restrict__ g_cursor) {
    __shared__ unsigned s[NBKT_PAD];
    int t = threadIdx.x;
    unsigned c = g_count[t];
    s[t] = c;
    __syncthreads();
    for (int off = 1; off < NBKT_PAD; off <<= 1) {
        unsigned v = (t >= off) ? s[t - off] : 0u;
        __syncthreads();
        s[t] += v;
        __syncthreads();
    }
    unsigned incl = s[t];
    g_base[t]   = incl - c;
    g_cursor[t] = incl - c;
    if (t == NBKT_PAD - 1) g_base[NBKT_PAD] = incl;
}

// P3: scatter edges into bucket-contiguous u64 records.
// rec = (src | dst_low11 << 20) << 32 | f32bits(weight)
// Write-locality design: 256 blocks x 489 buckets x ~2KB runs -> ~16MB active
// L2 line set (< 32MB aggregate) so the L2 merges scattered 8B writes into
// full lines. NO nontemporal stores (L2 merge is the whole point).
__global__ void scatter_kernel(const int* __restrict__ src,
                               const int* __restrict__ dst,
                               const float* __restrict__ ew,
                               unsigned* __restrict__ g_cursor,
                               unsigned long long* __restrict__ recs) {
    __shared__ unsigned lhist[NBKT_PAD];
    __shared__ unsigned lbase[NBKT_PAD];
    int e0 = blockIdx.x * SCAT_CHUNK;
    int e1 = e0 + SCAT_CHUNK;
    for (int j = threadIdx.x; j < NBKT_PAD; j += blockDim.x) lhist[j] = 0u;
    __syncthreads();
    for (int e = e0 + threadIdx.x; e < e1; e += blockDim.x)
        atomicAdd(&lhist[((unsigned)dst[e]) >> BKT_SHIFT], 1u);
    __syncthreads();
    for (int j = threadIdx.x; j < NBKT_PAD; j += blockDim.x) {
        unsigned c = lhist[j];
        lbase[j] = c ? atomicAdd(&g_cursor[j], c) : 0u;
    }
    __syncthreads();
    for (int j = threadIdx.x; j < NBKT_PAD; j += blockDim.x) lhist[j] = 0u;  // reuse as cursor
    __syncthreads();
    for (int e = e0 + threadIdx.x; e < e1; e += blockDim.x) {
        unsigned d = (unsigned)dst[e];
        unsigned b = d >> BKT_SHIFT;
        unsigned loc = atomicAdd(&lhist[b], 1u);
        unsigned pos = lbase[b] + loc;
        unsigned hi  = ((unsigned)src[e]) | ((d & (BKT_NODES - 1u)) << 20);
        recs[pos] = ((unsigned long long)hi << 32) | (unsigned)__float_as_uint(ew[e]);
    }
}

// ------------------------------ forward pass --------------------------------

// h0 = x; out[:,0] += per-graph sum of x
__global__ void init_kernel(const float* __restrict__ x,
                            const int* __restrict__ gids,
                            float* __restrict__ h0,
                            float* __restrict__ out) {
    int i = blockIdx.x * blockDim.x + threadIdx.x;
    if (i >= N_NODES) return;
    float v = x[i];
    h0[i] = v;
    seg_accum(gids[i], v, out, 0);
}

// One block per bucket: LDS-accumulate in-edges, then fused affine+relu,
// h double-buffer write, and per-graph sum for the block's 2048 owned nodes.
// Record stream is nontemporal (256MB/layer, read once) so the L2 keeps the
// 4MB h array resident for the random gather.
__global__ void layer_kernel(const unsigned long long* __restrict__ recs,
                             const unsigned* __restrict__ g_base,
                             const float* __restrict__ h_old,
                             float* __restrict__ h_new,
                             const int* __restrict__ gids,
                             const float* __restrict__ Wn,
                             const float* __restrict__ bn,
                             const float* __restrict__ Ws,
                             float* __restrict__ out,
                             int l) {
    __shared__ float agg[BKT_NODES];
    int b = blockIdx.x;
    for (int j = threadIdx.x; j < BKT_NODES; j += blockDim.x) agg[j] = 0.0f;
    __syncthreads();
    int e0 = (int)g_base[b];
    int e1 = (int)g_base[b + 1];
    for (int e = e0 + threadIdx.x; e < e1; e += blockDim.x) {
        unsigned long long rec = __builtin_nontemporal_load(&recs[e]);
        unsigned hi = (unsigned)(rec >> 32);
        float w  = __uint_as_float((unsigned)rec);
        float hv = h_old[hi & 0xFFFFFu];
        atomicAdd(&agg[hi >> 20], hv * w);
    }
    __syncthreads();
    float wn = Wn[l], bb = bn[l], ws = Ws[l];
    int nbase = b << BKT_SHIFT;
    for (int j = threadIdx.x; j < BKT_NODES; j += blockDim.x) {
        int n = nbase + j;
        if (n < N_NODES) {
            float hn = fmaxf(fmaf(agg[j], wn, fmaf(h_old[n], ws, bb)), 0.0f);
            h_new[n] = hn;
            seg_accum(gids[n], hn, out, l + 1);
        }
    }
}

// ------------------------- fallback (round-1 path) --------------------------

__global__ void fb_init_kernel(const float* __restrict__ x, const int* __restrict__ gids,
                               float* __restrict__ h, float* __restrict__ agg,
                               float* __restrict__ out) {
    int i = blockIdx.x * blockDim.x + threadIdx.x;
    if (i >= N_NODES) return;
    float v = x[i];
    h[i] = v; agg[i] = 0.0f;
    seg_accum(gids[i], v, out, 0);
}
__global__ void fb_edge_kernel(const int4* __restrict__ src4, const int4* __restrict__ dst4,
                               const float4* __restrict__ ew4, const float* __restrict__ h,
                               float* __restrict__ agg) {
    int t = blockIdx.x * blockDim.x + threadIdx.x;
    if (t >= N_EDGES / 4) return;
    int4 s = src4[t]; int4 d = dst4[t]; float4 w = ew4[t];
    atomicAdd(&agg[d.x], h[s.x] * w.x);
    atomicAdd(&agg[d.y], h[s.y] * w.y);
    atomicAdd(&agg[d.z], h[s.z] * w.z);
    atomicAdd(&agg[d.w], h[s.w] * w.w);
}
__global__ void fb_node_kernel(float* __restrict__ h, float* __restrict__ agg,
                               const int* __restrict__ gids, const float* __restrict__ Wn,
                               const float* __restrict__ bn, const float* __restrict__ Ws,
                               float* __restrict__ out, int l) {
    int i = blockIdx.x * blockDim.x + threadIdx.x;
    if (i >= N_NODES) return;
    float a = agg[i]; agg[i] = 0.0f;
    float hv = h[i];
    float hn = fmaxf(fmaf(a, Wn[l], fmaf(hv, Ws[l], bn[l])), 0.0f);
    h[i] = hn;
    seg_accum(gids[i], hn, out, l + 1);
}

// -----------------------------------------------------------------------------

extern "C" void kernel_launch(void* const* d_in, const int* in_sizes, int n_in,
                              void* d_out, int out_size, void* d_ws, size_t ws_size,
                              hipStream_t stream) {
    const float* x   = (const float*)d_in[0];
    const int*   src = (const int*)  d_in[1];
    const int*   dst = (const int*)  d_in[2];
    const float* ew  = (const float*)d_in[3];
    const int*   gid = (const int*)  d_in[4];
    const float* Wn  = (const float*)d_in[5];
    const float* bn  = (const float*)d_in[6];
    const float* Ws  = (const float*)d_in[7];
    float* out = (float*)d_out;

    hipMemsetAsync(d_out, 0, (size_t)out_size * sizeof(float), stream);

    size_t need = (size_t)N_EDGES * 8   // recs
                + (size_t)N_NODES * 4   // h0
                + (size_t)N_NODES * 4   // h1
                + (size_t)(NBKT_PAD * 3 + 16) * 4;

    if (ws_size < need) {
        // fallback: round-1 atomic path (needs 8 MB)
        float* h   = (float*)d_ws;
        float* agg = (float*)d_ws + N_NODES;
        const int BT = 256;
        const int nb = (N_NODES + BT - 1) / BT;
        const int eb = (N_EDGES / 4 + BT - 1) / BT;
        fb_init_kernel<<<nb, BT, 0, stream>>>(x, gid, h, agg, out);
        for (int l = 0; l < N_LAYERS; ++l) {
            fb_edge_kernel<<<eb, BT, 0, stream>>>(
                (const int4*)src, (const int4*)dst, (const float4*)ew, h, agg);
            fb_node_kernel<<<nb, BT, 0, stream>>>(h, agg, gid, Wn, bn, Ws, out, l);
        }
        return;
    }

    char* p = (char*)d_ws;
    unsigned long long* recs = (unsigned long long*)p;  p += (size_t)N_EDGES * 8;
    float*    h0       = (float*)p;                     p += (size_t)N_NODES * 4;
    float*    h1       = (float*)p;                     p += (size_t)N_NODES * 4;
    unsigned* g_count  = (unsigned*)p;                  p += NBKT_PAD * 4;
    unsigned* g_cursor = (unsigned*)p;                  p += NBKT_PAD * 4;
    unsigned* g_base   = (unsigned*)p;                  p += (NBKT_PAD + 1) * 4;

    // zero counters (g_count and g_cursor are adjacent)
    hipMemsetAsync(g_count, 0, NBKT_PAD * 2 * sizeof(unsigned), stream);

    // binning (once per call, amortized over 8 layers)
    count_kernel  <<<2048, 256, 0, stream>>>((const int4*)dst, g_count);
    scan_kernel   <<<1, NBKT_PAD, 0, stream>>>(g_count, g_base, g_cursor);
    scatter_kernel<<<SCAT_BLOCKS, SCAT_THREADS, 0, stream>>>(src, dst, ew, g_cursor, recs);

    // forward
    const int BT = 256;
    const int nb = (N_NODES + BT - 1) / BT;
    init_kernel<<<nb, BT, 0, stream>>>(x, gid, h0, out);

    float* ha = h0;
    float* hb = h1;
    for (int l = 0; l < N_LAYERS; ++l) {
        layer_kernel<<<NBKT, 512, 0, stream>>>(recs, g_base, ha, hb,
                                               gid, Wn, bn, Ws, out, l);
        float* t = ha; ha = hb; hb = t;
    }
}